// Round 9
// baseline (354.180 us; speedup 1.0000x reference)
//
#include <hip/hip_runtime.h>
#include <math.h>

#define B_ 8
#define C_ 128
#define N_ 64
#define T_ 512
#define H_ 4
#define D_ 32
#define OUT_ 128
#define E_ 256
#define EP_ 320   // E + N self-loops
#define NEG_SLOPE 0.2f
#define BN_EPS 1e-5f
#define NT_ (N_ * T_)

// ---- setup: wa[c][8] = W·att, edge lists, in-CSR (by dst), out-CSR (by src),
// ----        zero the pipeline counters (deterministic every launch)
__global__ void setup_kernel(const float* __restrict__ W,
                             const float* __restrict__ att_src,
                             const float* __restrict__ att_dst,
                             const int* __restrict__ edge_index,
                             float* __restrict__ wa,
                             int* __restrict__ esrc_g, int* __restrict__ edst_g,
                             int* __restrict__ iOff_g, int* __restrict__ iEid_g,
                             int* __restrict__ oOff_g, int* __restrict__ oEid_g,
                             int* __restrict__ ctr) {
  __shared__ int icnt[N_], ibase[N_ + 1], ifill[N_];
  __shared__ int ocnt[N_], obase[N_ + 1], ofill[N_];
  __shared__ int esrc[EP_], edst[EP_];
  int tid = threadIdx.x;

  if (tid < 24) ctr[tid] = 0;   // ctrA1[8], ctrA2[8], ctrB1[8]

  for (int idx = tid; idx < C_ * 8; idx += blockDim.x) {
    int c = idx >> 3, j = idx & 7, h = j & 3;
    const float* att = (j < 4) ? att_src : att_dst;
    float s = 0.f;
    for (int d = 0; d < D_; ++d)
      s += W[(c * H_ + h) * D_ + d] * att[h * D_ + d];
    wa[idx] = s;
  }
  if (tid < N_) { icnt[tid] = 0; ifill[tid] = 0; ocnt[tid] = 0; ofill[tid] = 0; }
  __syncthreads();
  for (int e = tid; e < EP_; e += blockDim.x) {
    int s, d;
    if (e < E_) { s = edge_index[e]; d = edge_index[E_ + e]; }
    else        { s = e - E_;        d = e - E_; }
    esrc[e] = s; edst[e] = d;
    atomicAdd(&icnt[d], 1);
    atomicAdd(&ocnt[s], 1);
  }
  __syncthreads();
  if (tid == 0) {
    int ai = 0, ao = 0;
    for (int n = 0; n < N_; ++n) {
      ibase[n] = ai; ai += icnt[n];
      obase[n] = ao; ao += ocnt[n];
    }
    ibase[N_] = ai; obase[N_] = ao;
  }
  __syncthreads();
  if (tid <= N_) { iOff_g[tid] = ibase[tid]; oOff_g[tid] = obase[tid]; }
  for (int e = tid; e < EP_; e += blockDim.x) {
    esrc_g[e] = esrc[e]; edst_g[e] = edst[e];
    int d = edst[e];
    int pi = ibase[d] + atomicAdd(&ifill[d], 1);
    iEid_g[pi] = e;
    int s = esrc[e];
    int po = obase[s] + atomicAdd(&ofill[s], 1);
    oEid_g[po] = e;
  }
}

// ---- persistent two-team pipeline kernel, grid = 256, block = 256 -------------
// team A (even bid): per b: P1 proj (x pass 1, streamed) -> barrier ->
//                    P2 segment-softmax weights -> release ctrA2[b]
// team B (odd bid):  per b: acquire ctrA2[b] -> P3 aggregation (x pass 2,
//                    streamed) -> barrier -> P4 y·W + bias + BN -> out
// Steady state: P1(b+1) on team A overlaps P3(b) on team B.

__device__ inline void arrive_rel(int* c) {
  __syncthreads();
  if (threadIdx.x == 0)
    __hip_atomic_fetch_add(c, 1, __ATOMIC_RELEASE, __HIP_MEMORY_SCOPE_AGENT);
}
__device__ inline void wait_acq(int* c, int target) {
  if (threadIdx.x == 0) {
    while (__hip_atomic_load(c, __ATOMIC_ACQUIRE, __HIP_MEMORY_SCOPE_AGENT) < target)
      __builtin_amdgcn_s_sleep(8);
  }
  __syncthreads();
}

#define ARENA_BYTES 71680
// team A layout: red4 @0 (32KB) | wal @32768 (4KB) | a_l @36864 (8KB)
//                sc @45056 (20KB) | edges @65536 (~5.6KB)
// team B layout: w_t @0 (16.9KB) | wl @20480 (16KB)

__global__ __launch_bounds__(256, 2)
void mega_kernel(const float* __restrict__ x,
                 const float* __restrict__ wa_g,
                 const float* __restrict__ Wm,
                 const int* __restrict__ esrc_g, const int* __restrict__ edst_g,
                 const int* __restrict__ iOff_g, const int* __restrict__ iEid_g,
                 const int* __restrict__ oOff_g, const int* __restrict__ oEid_g,
                 const float* __restrict__ bias,
                 const float* __restrict__ bn_gamma,
                 const float* __restrict__ bn_beta,
                 const float* __restrict__ bn_mean,
                 const float* __restrict__ bn_var,
                 float* a2, float* w_ws, float* y_ws, int* ctr,
                 float* __restrict__ out) {
  __shared__ __align__(16) char arena[ARENA_BYTES];
  int* ctrA1 = ctr;
  int* ctrA2 = ctr + 8;
  int* ctrB1 = ctr + 16;

  const int tid = threadIdx.x;
  const int team = blockIdx.x & 1;
  const int r = blockIdx.x >> 1;          // 0..127

  if (team == 0) {
    // =================== TEAM A ===================
    float4* red4 = (float4*)arena;                       // [4][8][64]
    float*  wal  = (float*)(arena + 32768);              // [128][8]
    float*  a_l  = (float*)(arena + 36864);              // [8][64][4]
    float4* sc   = (float4*)(arena + 45056);             // [320][4]
    int* eS   = (int*)(arena + 65536);
    int* eD   = eS + EP_;
    int* iEid = eD + EP_;
    int* oEid = iEid + EP_;
    int* iOff = oEid + EP_;
    int* oOff = iOff + (N_ + 1);

    for (int i = tid; i < C_ * 8; i += 256) wal[i] = wa_g[i];
    for (int i = tid; i < EP_; i += 256) {
      eS[i] = esrc_g[i]; eD[i] = edst_g[i];
      iEid[i] = iEid_g[i]; oEid[i] = oEid_g[i];
    }
    if (tid <= N_) { iOff[tid] = iOff_g[tid]; oOff[tid] = oOff_g[tid]; }
    __syncthreads();

    const int n  = r >> 1;                 // node 0..63
    const int th = r & 1;                  // T-half
    const int cg = tid >> 6, tq = tid & 63;
    const int tc4 = r;                     // P2 role: t4-chunk 0..127

    for (int b = 0; b < B_; ++b) {
      // ---- P1: a[j] for (n, t = th*256 + tq*4 ..+3), reduce over c ----
      {
        const float* xp = x + ((size_t)(b * C_) * N_ + n) * T_ + th * 256 + tq * 4;
        float4 acc[8];
#pragma unroll
        for (int j = 0; j < 8; ++j) { acc[j].x = 0.f; acc[j].y = 0.f; acc[j].z = 0.f; acc[j].w = 0.f; }
        for (int kb = 0; kb < 4; ++kb) {
          float4 xv[8];
#pragma unroll
          for (int u = 0; u < 8; ++u) {
            int c = cg + (kb * 8 + u) * 4;
            xv[u] = *reinterpret_cast<const float4*>(xp + (size_t)c * NT_);
          }
#pragma unroll
          for (int u = 0; u < 8; ++u) {
            int c = cg + (kb * 8 + u) * 4;
            const float4 w0 = *reinterpret_cast<const float4*>(&wal[c * 8]);
            const float4 w1 = *reinterpret_cast<const float4*>(&wal[c * 8 + 4]);
            float4 xu = xv[u];
            acc[0].x = fmaf(xu.x, w0.x, acc[0].x); acc[0].y = fmaf(xu.y, w0.x, acc[0].y);
            acc[0].z = fmaf(xu.z, w0.x, acc[0].z); acc[0].w = fmaf(xu.w, w0.x, acc[0].w);
            acc[1].x = fmaf(xu.x, w0.y, acc[1].x); acc[1].y = fmaf(xu.y, w0.y, acc[1].y);
            acc[1].z = fmaf(xu.z, w0.y, acc[1].z); acc[1].w = fmaf(xu.w, w0.y, acc[1].w);
            acc[2].x = fmaf(xu.x, w0.z, acc[2].x); acc[2].y = fmaf(xu.y, w0.z, acc[2].y);
            acc[2].z = fmaf(xu.z, w0.z, acc[2].z); acc[2].w = fmaf(xu.w, w0.z, acc[2].w);
            acc[3].x = fmaf(xu.x, w0.w, acc[3].x); acc[3].y = fmaf(xu.y, w0.w, acc[3].y);
            acc[3].z = fmaf(xu.z, w0.w, acc[3].z); acc[3].w = fmaf(xu.w, w0.w, acc[3].w);
            acc[4].x = fmaf(xu.x, w1.x, acc[4].x); acc[4].y = fmaf(xu.y, w1.x, acc[4].y);
            acc[4].z = fmaf(xu.z, w1.x, acc[4].z); acc[4].w = fmaf(xu.w, w1.x, acc[4].w);
            acc[5].x = fmaf(xu.x, w1.y, acc[5].x); acc[5].y = fmaf(xu.y, w1.y, acc[5].y);
            acc[5].z = fmaf(xu.z, w1.y, acc[5].z); acc[5].w = fmaf(xu.w, w1.y, acc[5].w);
            acc[6].x = fmaf(xu.x, w1.z, acc[6].x); acc[6].y = fmaf(xu.y, w1.z, acc[6].y);
            acc[6].z = fmaf(xu.z, w1.z, acc[6].z); acc[6].w = fmaf(xu.w, w1.z, acc[6].w);
            acc[7].x = fmaf(xu.x, w1.w, acc[7].x); acc[7].y = fmaf(xu.y, w1.w, acc[7].y);
            acc[7].z = fmaf(xu.z, w1.w, acc[7].z); acc[7].w = fmaf(xu.w, w1.w, acc[7].w);
          }
        }
#pragma unroll
        for (int j = 0; j < 8; ++j) red4[(cg * 8 + j) * 64 + tq] = acc[j];
        __syncthreads();
#pragma unroll
        for (int rep = 0; rep < 2; ++rep) {
          int ss = tid + rep * 256;
          int j = ss >> 6, tq2 = ss & 63;
          float4 v0 = red4[(0 * 8 + j) * 64 + tq2];
          float4 v1 = red4[(1 * 8 + j) * 64 + tq2];
          float4 v2 = red4[(2 * 8 + j) * 64 + tq2];
          float4 v3 = red4[(3 * 8 + j) * 64 + tq2];
          float4 rr;
          rr.x = (v0.x + v1.x) + (v2.x + v3.x);
          rr.y = (v0.y + v1.y) + (v2.y + v3.y);
          rr.z = (v0.z + v1.z) + (v2.z + v3.z);
          rr.w = (v0.w + v1.w) + (v2.w + v3.w);
          int tc = th * 32 + (tq2 >> 1);
          reinterpret_cast<float4*>(a2)[(((size_t)(b * 64 + tc) * 64 + n) * 8 + j) * 2 + (tq2 & 1)] = rr;
        }
        __syncthreads();
      }
      // ---- a2[b] complete across team A ----
      arrive_rel(&ctrA1[b]);
      wait_acq(&ctrA1[b], 128);

      // ---- P2: segment softmax for t4-chunk tc4; write w_ws[b][n][h][t] ----
      {
        const int tc8 = tc4 >> 1, hf = tc4 & 1;
        // load a-slice [64n][8j][4t]
#pragma unroll
        for (int f = 0; f < 2; ++f) {
          int fidx = tid * 2 + f;
          int nn = fidx >> 3, j = fidx & 7;
          float4 v = reinterpret_cast<const float4*>(a2)[(((size_t)(b * 64 + tc8) * 64 + nn) * 8 + j) * 2 + hf];
          *reinterpret_cast<float4*>(&a_l[(j * 64 + nn) * 4]) = v;
        }
        __syncthreads();
        // scores + leaky relu (EP*4 items)
        for (int idx = tid; idx < EP_ * 4; idx += 256) {
          int e = idx >> 2, t = idx & 3;
          int s = eS[e], d = eD[e];
          float4 v;
          v.x = a_l[(0 * 64 + s) * 4 + t] + a_l[(4 * 64 + d) * 4 + t];
          v.y = a_l[(1 * 64 + s) * 4 + t] + a_l[(5 * 64 + d) * 4 + t];
          v.z = a_l[(2 * 64 + s) * 4 + t] + a_l[(6 * 64 + d) * 4 + t];
          v.w = a_l[(3 * 64 + s) * 4 + t] + a_l[(7 * 64 + d) * 4 + t];
          v.x = v.x > 0.f ? v.x : NEG_SLOPE * v.x;
          v.y = v.y > 0.f ? v.y : NEG_SLOPE * v.y;
          v.z = v.z > 0.f ? v.z : NEG_SLOPE * v.z;
          v.w = v.w > 0.f ? v.w : NEG_SLOPE * v.w;
          sc[e * 4 + t] = v;
        }
        __syncthreads();
        // per (dst,t) softmax, rescale in place (owner-writes)
        {
          int nd = tid >> 2, t = tid & 3;
          int e0 = iOff[nd], e1 = iOff[nd + 1];
          float m0 = -1e30f, m1 = -1e30f, m2 = -1e30f, m3 = -1e30f;
          for (int e = e0; e < e1; ++e) {
            float4 v = sc[iEid[e] * 4 + t];
            m0 = fmaxf(m0, v.x); m1 = fmaxf(m1, v.y);
            m2 = fmaxf(m2, v.z); m3 = fmaxf(m3, v.w);
          }
          float d0 = 0.f, d1 = 0.f, d2 = 0.f, d3 = 0.f;
          for (int e = e0; e < e1; ++e) {
            float4 v = sc[iEid[e] * 4 + t];
            d0 += __expf(v.x - m0); d1 += __expf(v.y - m1);
            d2 += __expf(v.z - m2); d3 += __expf(v.w - m3);
          }
          float i0 = 1.f / (d0 * (float)N_);   // fold mean 1/N
          float i1 = 1.f / (d1 * (float)N_);
          float i2 = 1.f / (d2 * (float)N_);
          float i3 = 1.f / (d3 * (float)N_);
          for (int e = e0; e < e1; ++e) {
            int ee = iEid[e];
            float4 v = sc[ee * 4 + t];
            v.x = __expf(v.x - m0) * i0; v.y = __expf(v.y - m1) * i1;
            v.z = __expf(v.z - m2) * i2; v.w = __expf(v.w - m3) * i3;
            sc[ee * 4 + t] = v;
          }
        }
        __syncthreads();
        // per (src,t) gather -> w_ws[b][src][h][tc4*4 + t]
        {
          int src = tid >> 2, t = tid & 3;
          int e0 = oOff[src], e1 = oOff[src + 1];
          float4 acc = {0.f, 0.f, 0.f, 0.f};
          for (int e = e0; e < e1; ++e) {
            float4 v = sc[oEid[e] * 4 + t];
            acc.x += v.x; acc.y += v.y; acc.z += v.z; acc.w += v.w;
          }
          size_t base = ((size_t)(b * 64 + src) * 4) * 512 + tc4 * 4 + t;
          w_ws[base]         = acc.x;
          w_ws[base + 512]   = acc.y;
          w_ws[base + 1024]  = acc.z;
          w_ws[base + 1536]  = acc.w;
        }
      }
      arrive_rel(&ctrA2[b]);   // w[b] ready; move on (no spin)
    }
  } else {
    // =================== TEAM B ===================
    float* w_t = (float*)arena;                 // [64t][65] (h*16+i packing)
    float* wl  = (float*)(arena + 20480);       // W[:,h,:] 16KB
    const int cs8 = r & 15, c0 = cs8 * 8;
    const int tq4 = r >> 4;                     // 0..7 (64-t slabs)
    const int tl = tid & 63, cpair = tid >> 6;  // compute mapping
    const int hP4 = r >> 5, t0o = (r & 31) * 16;// P4 role

    // stage W[:,hP4,:] once (region untouched by P3)
    for (int i = tid; i < C_ * D_; i += 256) {
      int c = i >> 5, d = i & 31;
      wl[i] = Wm[((size_t)c * H_ + hP4) * D_ + d];
    }
    __syncthreads();

    for (int b = 0; b < B_; ++b) {
      wait_acq(&ctrA2[b], 128);
      // ---- P3: y[h][c][t] = sum_n w[n][h][t] * x[c][n][t] ----
      float y00 = 0.f, y01 = 0.f, y02 = 0.f, y03 = 0.f;
      float y10 = 0.f, y11 = 0.f, y12 = 0.f, y13 = 0.f;
      const int cA = c0 + cpair * 2, cB = cA + 1;
      const int t = tq4 * 64 + tl;
      const float* xbA = x + ((size_t)(b * C_ + cA) * N_) * T_ + t;
      const float* xbB = x + ((size_t)(b * C_ + cB) * N_) * T_ + t;
      for (int nc = 0; nc < 4; ++nc) {
        // stage w_t[tl][h*16+i] for n = nc*16+i, t = tq4*64 + tl
        {
          int i2 = tid >> 2, lane4 = tid & 3;
          int i = i2 & 15, h = i2 >> 4;
          const float* wp = w_ws + ((size_t)(b * 64 + nc * 16 + i) * 4 + h) * 512 + tq4 * 64;
#pragma unroll
          for (int f = 0; f < 4; ++f) {
            int tq = f * 4 + lane4;
            float4 v = *reinterpret_cast<const float4*>(wp + tq * 4);
            w_t[(tq * 4 + 0) * 65 + h * 16 + i] = v.x;
            w_t[(tq * 4 + 1) * 65 + h * 16 + i] = v.y;
            w_t[(tq * 4 + 2) * 65 + h * 16 + i] = v.z;
            w_t[(tq * 4 + 3) * 65 + h * 16 + i] = v.w;
          }
        }
        __syncthreads();
        // batch the 32 x loads, then FMA with conflict-free w_t reads
        float xr[32];
#pragma unroll
        for (int i = 0; i < 16; ++i) {
          int nn = nc * 16 + i;
          xr[i * 2]     = xbA[(size_t)nn * T_];
          xr[i * 2 + 1] = xbB[(size_t)nn * T_];
        }
#pragma unroll
        for (int i = 0; i < 16; ++i) {
          float w0 = w_t[tl * 65 + i];
          float w1 = w_t[tl * 65 + 16 + i];
          float w2 = w_t[tl * 65 + 32 + i];
          float w3 = w_t[tl * 65 + 48 + i];
          float xA = xr[i * 2], xB = xr[i * 2 + 1];
          y00 = fmaf(xA, w0, y00); y01 = fmaf(xA, w1, y01);
          y02 = fmaf(xA, w2, y02); y03 = fmaf(xA, w3, y03);
          y10 = fmaf(xB, w0, y10); y11 = fmaf(xB, w1, y11);
          y12 = fmaf(xB, w2, y12); y13 = fmaf(xB, w3, y13);
        }
        __syncthreads();
      }
      {
        size_t yb = ((size_t)(b * H_) * C_ + cA) * T_ + t;
        const size_t hs = (size_t)C_ * T_;
        y_ws[yb]          = y00; y_ws[yb + hs]     = y01;
        y_ws[yb + 2 * hs] = y02; y_ws[yb + 3 * hs] = y03;
        y_ws[yb + 512]          = y10; y_ws[yb + hs + 512]     = y11;
        y_ws[yb + 2 * hs + 512] = y12; y_ws[yb + 3 * hs + 512] = y13;
      }
      arrive_rel(&ctrB1[b]);
      wait_acq(&ctrB1[b], 128);
      // ---- P4: out[oc][t] = BN(sum_c y[h][c][t]*W[c][h][d] + bias) ----
      {
        const int tl4 = tid & 15, dg = tid >> 4;   // 2 d's per thread
        float acc0 = 0.f, acc1 = 0.f;
        const float* yp = y_ws + ((size_t)(b * H_ + hP4) * C_) * T_ + t0o + tl4;
#pragma unroll 4
        for (int c = 0; c < C_; ++c) {
          float yv = yp[(size_t)c * T_];
          acc0 = fmaf(yv, wl[c * D_ + dg * 2], acc0);
          acc1 = fmaf(yv, wl[c * D_ + dg * 2 + 1], acc1);
        }
        int oc0 = hP4 * D_ + dg * 2;
        float s0 = bn_gamma[oc0] * rsqrtf(bn_var[oc0] + BN_EPS);
        float s1 = bn_gamma[oc0 + 1] * rsqrtf(bn_var[oc0 + 1] + BN_EPS);
        out[((size_t)b * OUT_ + oc0) * T_ + t0o + tl4] =
            (acc0 + bias[oc0]) * s0 + bn_beta[oc0] - bn_mean[oc0] * s0;
        out[((size_t)b * OUT_ + oc0 + 1) * T_ + t0o + tl4] =
            (acc1 + bias[oc0 + 1]) * s1 + bn_beta[oc0 + 1] - bn_mean[oc0 + 1] * s1;
      }
      __syncthreads();
    }
  }
}

extern "C" void kernel_launch(void* const* d_in, const int* in_sizes, int n_in,
                              void* d_out, int out_size, void* d_ws, size_t ws_size,
                              hipStream_t stream) {
  const float* x        = (const float*)d_in[0];
  const float* W        = (const float*)d_in[1];
  const float* att_src  = (const float*)d_in[2];
  const float* att_dst  = (const float*)d_in[3];
  const float* bias     = (const float*)d_in[4];
  const float* bn_gamma = (const float*)d_in[5];
  const float* bn_beta  = (const float*)d_in[6];
  const float* bn_mean  = (const float*)d_in[7];
  const float* bn_var   = (const float*)d_in[8];
  const int* edge_index = (const int*)d_in[9];
  float* out = (float*)d_out;

  char* ws = (char*)d_ws;
  float* wa    = (float*)ws;                  // 4 KB
  int* esrc_g  = (int*)(ws + 4096);
  int* edst_g  = (int*)(ws + 6144);
  int* iOff_g  = (int*)(ws + 8192);
  int* iEid_g  = (int*)(ws + 8704);
  int* oOff_g  = (int*)(ws + 10752);
  int* oEid_g  = (int*)(ws + 11264);
  int* ctr     = (int*)(ws + 12800);          // 24 counters
  float* a2    = (float*)(ws + 16384);        // 8 MB  [b][tc8][n][j][8t]
  float* w_ws  = (float*)(ws + 16384 + (size_t)8 * 1024 * 1024);   // 4 MB [b][n][h][t]
  float* y_ws  = (float*)(ws + 16384 + (size_t)12 * 1024 * 1024);  // 8 MB [b][h][c][t]

  setup_kernel<<<1, 256, 0, stream>>>(W, att_src, att_dst, edge_index, wa,
                                      esrc_g, edst_g, iOff_g, iEid_g,
                                      oOff_g, oEid_g, ctr);
  mega_kernel<<<256, 256, 0, stream>>>(x, wa, W, esrc_g, edst_g,
                                       iOff_g, iEid_g, oOff_g, oEid_g,
                                       bias, bn_gamma, bn_beta, bn_mean, bn_var,
                                       a2, w_ws, y_ws, ctr, out);
}

// Round 10
// 73.304 us; speedup vs baseline: 4.8317x; 4.8317x over previous
//
#include <hip/hip_runtime.h>
#include <math.h>

#define B_ 8
#define C_ 128
#define N_ 64
#define T_ 512
#define H_ 4
#define D_ 32
#define OUT_ 128
#define E_ 256
#define EP_ 320   // E + N self-loops
#define NEG_SLOPE 0.2f
#define BN_EPS 1e-5f
#define TC 16     // time steps per block
#define NT_ (N_ * T_)

// ---- setup: wa[c][8] = W·att; in-list (src per in-edge, grouped by dst);
// ----        out-list (dst per out-edge, grouped by src)
__global__ void setup_kernel(const float* __restrict__ W,
                             const float* __restrict__ att_src,
                             const float* __restrict__ att_dst,
                             const int* __restrict__ edge_index,
                             float* __restrict__ wa,
                             int* __restrict__ iOff_g, int* __restrict__ iSrc_g,
                             int* __restrict__ oOff_g, int* __restrict__ oDst_g) {
  __shared__ int icnt[N_], ibase[N_ + 1], ifill[N_];
  __shared__ int ocnt[N_], obase[N_ + 1], ofill[N_];
  __shared__ int esrc[EP_], edst[EP_];
  int tid = threadIdx.x;

  for (int idx = tid; idx < C_ * 8; idx += blockDim.x) {
    int c = idx >> 3, j = idx & 7, h = j & 3;
    const float* att = (j < 4) ? att_src : att_dst;
    float s = 0.f;
    for (int d = 0; d < D_; ++d)
      s += W[(c * H_ + h) * D_ + d] * att[h * D_ + d];
    wa[idx] = s;
  }
  if (tid < N_) { icnt[tid] = 0; ifill[tid] = 0; ocnt[tid] = 0; ofill[tid] = 0; }
  __syncthreads();
  for (int e = tid; e < EP_; e += blockDim.x) {
    int s, d;
    if (e < E_) { s = edge_index[e]; d = edge_index[E_ + e]; }
    else        { s = e - E_;        d = e - E_; }
    esrc[e] = s; edst[e] = d;
    atomicAdd(&icnt[d], 1);
    atomicAdd(&ocnt[s], 1);
  }
  __syncthreads();
  if (tid == 0) {
    int ai = 0, ao = 0;
    for (int n = 0; n < N_; ++n) {
      ibase[n] = ai; ai += icnt[n];
      obase[n] = ao; ao += ocnt[n];
    }
    ibase[N_] = ai; obase[N_] = ao;
  }
  __syncthreads();
  if (tid <= N_) { iOff_g[tid] = ibase[tid]; oOff_g[tid] = obase[tid]; }
  for (int e = tid; e < EP_; e += blockDim.x) {
    int s = esrc[e], d = edst[e];
    int pi = ibase[d] + atomicAdd(&ifill[d], 1);
    iSrc_g[pi] = s;
    int po = obase[s] + atomicAdd(&ofill[s], 1);
    oDst_g[po] = d;
  }
}

// ---- megakernel: one block per (b, 16-t chunk). grid = 256, block = 1024.
// 1 block/CU -> 16 waves/CU (4/SIMD) for latency hiding. Phases:
// P1 proj (c split 4-way, LDS pairwise reduce) -> softmax B (z) -> C (w) ->
// P2 agg (c split 64-way) -> P3 y·W + bias + BN (W staged in LDS).
__global__ __launch_bounds__(1024, 1)
void mega_kernel(const float* __restrict__ x,
                 const float* __restrict__ wa_g,
                 const float* __restrict__ Wm,
                 const int* __restrict__ iOff_g, const int* __restrict__ iSrc_g,
                 const int* __restrict__ oOff_g, const int* __restrict__ oDst_g,
                 const float* __restrict__ bias,
                 const float* __restrict__ bn_gamma,
                 const float* __restrict__ bn_beta,
                 const float* __restrict__ bn_mean,
                 const float* __restrict__ bn_var,
                 float* __restrict__ out) {
  __shared__ __align__(16) char arena[114688];
  float* a_l   = (float*)arena;                     // [8][64][20] 40960B; y overlay [4][128][17]
  float4* redA = (float4*)(arena + 40960);          // 32KB (pass1 scratch)
  float4* redB = (float4*)(arena + 73728);          // 32KB (pass1 scratch)
  float* z_l   = (float*)(arena + 40960);           // [64][16][4] 16KB (post-P1)
  float* w_l   = (float*)(arena + 57344);           // [n*64+h*16+t] 16KB (post-P1)
  float* wstage= (float*)(arena + 40960);           // 64KB W stage (P3)
  float* wal   = (float*)(arena + 106496);          // 4KB
  int* iSrc = (int*)(arena + 110592);
  int* oDst = iSrc + EP_;
  int* iOff = oDst + EP_;
  int* oOff = iOff + (N_ + 1);

  const int tid = threadIdx.x;
  const int b = blockIdx.x & 7;              // batch -> XCD pinning
  const int tchunk = blockIdx.x >> 3;        // 0..31
  const int t0 = tchunk * TC;

  if (tid < EP_) { iSrc[tid] = iSrc_g[tid]; oDst[tid] = oDst_g[tid]; }
  if (tid >= EP_ && tid < EP_ + N_ + 1) {
    int i = tid - EP_;
    iOff[i] = iOff_g[i]; oOff[i] = oOff_g[i];
  }
  if (tid < C_ * 8) wal[tid] = wa_g[tid];
  __syncthreads();

  // ---------------- pass 1: a[j][n][t] = sum_c x[b][c][n][t]*wa[c][j] ----------
  {
    const int q  = tid & 3;          // t-quad
    const int cq = (tid >> 2) & 3;   // c quarter
    const int n1 = tid >> 4;         // node 0..63
    const float* xp = x + ((size_t)(b * C_ + cq * 32) * N_ + n1) * T_ + t0 + q * 4;
    float4 acc[8];
#pragma unroll
    for (int j = 0; j < 8; ++j) { acc[j].x = 0.f; acc[j].y = 0.f; acc[j].z = 0.f; acc[j].w = 0.f; }
    for (int kb = 0; kb < 4; ++kb) {
      float4 xv[8];
#pragma unroll
      for (int u = 0; u < 8; ++u)
        xv[u] = *reinterpret_cast<const float4*>(xp + (size_t)(kb * 8 + u) * NT_);
#pragma unroll
      for (int u = 0; u < 8; ++u) {
        const int c = cq * 32 + kb * 8 + u;
        const float4 w0 = *reinterpret_cast<const float4*>(&wal[c * 8]);
        const float4 w1 = *reinterpret_cast<const float4*>(&wal[c * 8 + 4]);
        const float4 xu = xv[u];
        acc[0].x = fmaf(xu.x, w0.x, acc[0].x); acc[0].y = fmaf(xu.y, w0.x, acc[0].y);
        acc[0].z = fmaf(xu.z, w0.x, acc[0].z); acc[0].w = fmaf(xu.w, w0.x, acc[0].w);
        acc[1].x = fmaf(xu.x, w0.y, acc[1].x); acc[1].y = fmaf(xu.y, w0.y, acc[1].y);
        acc[1].z = fmaf(xu.z, w0.y, acc[1].z); acc[1].w = fmaf(xu.w, w0.y, acc[1].w);
        acc[2].x = fmaf(xu.x, w0.z, acc[2].x); acc[2].y = fmaf(xu.y, w0.z, acc[2].y);
        acc[2].z = fmaf(xu.z, w0.z, acc[2].z); acc[2].w = fmaf(xu.w, w0.z, acc[2].w);
        acc[3].x = fmaf(xu.x, w0.w, acc[3].x); acc[3].y = fmaf(xu.y, w0.w, acc[3].y);
        acc[3].z = fmaf(xu.z, w0.w, acc[3].z); acc[3].w = fmaf(xu.w, w0.w, acc[3].w);
        acc[4].x = fmaf(xu.x, w1.x, acc[4].x); acc[4].y = fmaf(xu.y, w1.x, acc[4].y);
        acc[4].z = fmaf(xu.z, w1.x, acc[4].z); acc[4].w = fmaf(xu.w, w1.x, acc[4].w);
        acc[5].x = fmaf(xu.x, w1.y, acc[5].x); acc[5].y = fmaf(xu.y, w1.y, acc[5].y);
        acc[5].z = fmaf(xu.z, w1.y, acc[5].z); acc[5].w = fmaf(xu.w, w1.y, acc[5].w);
        acc[6].x = fmaf(xu.x, w1.z, acc[6].x); acc[6].y = fmaf(xu.y, w1.z, acc[6].y);
        acc[6].z = fmaf(xu.z, w1.z, acc[6].z); acc[6].w = fmaf(xu.w, w1.z, acc[6].w);
        acc[7].x = fmaf(xu.x, w1.w, acc[7].x); acc[7].y = fmaf(xu.y, w1.w, acc[7].y);
        acc[7].z = fmaf(xu.z, w1.w, acc[7].z); acc[7].w = fmaf(xu.w, w1.w, acc[7].w);
      }
    }
    // 2-stage pairwise reduce: cq1 -> redA, cq3 -> redB
    if (cq == 1) {
#pragma unroll
      for (int j = 0; j < 8; ++j) redA[(j * 64 + n1) * 4 + q] = acc[j];
    } else if (cq == 3) {
#pragma unroll
      for (int j = 0; j < 8; ++j) redB[(j * 64 + n1) * 4 + q] = acc[j];
    }
    __syncthreads();
    if (cq == 0) {
#pragma unroll
      for (int j = 0; j < 8; ++j) {
        float4 o = redA[(j * 64 + n1) * 4 + q];
        acc[j].x += o.x; acc[j].y += o.y; acc[j].z += o.z; acc[j].w += o.w;
      }
    } else if (cq == 2) {
#pragma unroll
      for (int j = 0; j < 8; ++j) {
        float4 o = redB[(j * 64 + n1) * 4 + q];
        acc[j].x += o.x; acc[j].y += o.y; acc[j].z += o.z; acc[j].w += o.w;
        redB[(j * 64 + n1) * 4 + q] = acc[j];
      }
    }
    __syncthreads();
    if (cq == 0) {
#pragma unroll
      for (int j = 0; j < 8; ++j) {
        float4 o = redB[(j * 64 + n1) * 4 + q];
        float4 r;
        r.x = acc[j].x + o.x; r.y = acc[j].y + o.y;
        r.z = acc[j].z + o.z; r.w = acc[j].w + o.w;
        *reinterpret_cast<float4*>(&a_l[j * 1280 + n1 * 20 + q * 4]) = r;
      }
    }
    __syncthreads();
  }

  // ---------------- softmax B: per (dst,t): z = exp(-m)/(den*N) ----------------
  {
    const int t = tid & 15, nd = tid >> 4;   // exactly 64x16 = 1024 items
    int e0 = iOff[nd], e1 = iOff[nd + 1];
    float ad0 = a_l[4 * 1280 + nd * 20 + t];
    float ad1 = a_l[5 * 1280 + nd * 20 + t];
    float ad2 = a_l[6 * 1280 + nd * 20 + t];
    float ad3 = a_l[7 * 1280 + nd * 20 + t];
    float m0 = -1e30f, m1 = -1e30f, m2 = -1e30f, m3 = -1e30f;
    for (int e = e0; e < e1; ++e) {
      int s = iSrc[e];
      float v0 = a_l[0 * 1280 + s * 20 + t] + ad0; v0 = v0 > 0.f ? v0 : NEG_SLOPE * v0;
      float v1 = a_l[1 * 1280 + s * 20 + t] + ad1; v1 = v1 > 0.f ? v1 : NEG_SLOPE * v1;
      float v2 = a_l[2 * 1280 + s * 20 + t] + ad2; v2 = v2 > 0.f ? v2 : NEG_SLOPE * v2;
      float v3 = a_l[3 * 1280 + s * 20 + t] + ad3; v3 = v3 > 0.f ? v3 : NEG_SLOPE * v3;
      m0 = fmaxf(m0, v0); m1 = fmaxf(m1, v1);
      m2 = fmaxf(m2, v2); m3 = fmaxf(m3, v3);
    }
    float d0 = 0.f, d1 = 0.f, d2 = 0.f, d3 = 0.f;
    for (int e = e0; e < e1; ++e) {
      int s = iSrc[e];
      float v0 = a_l[0 * 1280 + s * 20 + t] + ad0; v0 = v0 > 0.f ? v0 : NEG_SLOPE * v0;
      float v1 = a_l[1 * 1280 + s * 20 + t] + ad1; v1 = v1 > 0.f ? v1 : NEG_SLOPE * v1;
      float v2 = a_l[2 * 1280 + s * 20 + t] + ad2; v2 = v2 > 0.f ? v2 : NEG_SLOPE * v2;
      float v3 = a_l[3 * 1280 + s * 20 + t] + ad3; v3 = v3 > 0.f ? v3 : NEG_SLOPE * v3;
      d0 += __expf(v0 - m0); d1 += __expf(v1 - m1);
      d2 += __expf(v2 - m2); d3 += __expf(v3 - m3);
    }
    float4 zv;
    zv.x = __expf(-m0) / (d0 * (float)N_);
    zv.y = __expf(-m1) / (d1 * (float)N_);
    zv.z = __expf(-m2) / (d2 * (float)N_);
    zv.w = __expf(-m3) / (d3 * (float)N_);
    __syncthreads();   // a_l stable; z region (redA alias) free after P1
    *reinterpret_cast<float4*>(&z_l[(nd * 16 + t) * 4]) = zv;
  }
  __syncthreads();

  // ---------------- softmax C: per (src,t) gather -> w[n][h][t] ----------------
  {
    const int t = tid & 15, src = tid >> 4;
    int e0 = oOff[src], e1 = oOff[src + 1];
    float as0 = a_l[0 * 1280 + src * 20 + t];
    float as1 = a_l[1 * 1280 + src * 20 + t];
    float as2 = a_l[2 * 1280 + src * 20 + t];
    float as3 = a_l[3 * 1280 + src * 20 + t];
    float w0 = 0.f, w1 = 0.f, w2 = 0.f, w3 = 0.f;
    for (int e = e0; e < e1; ++e) {
      int d = oDst[e];
      float4 zv = *reinterpret_cast<const float4*>(&z_l[(d * 16 + t) * 4]);
      float v0 = as0 + a_l[4 * 1280 + d * 20 + t]; v0 = v0 > 0.f ? v0 : NEG_SLOPE * v0;
      float v1 = as1 + a_l[5 * 1280 + d * 20 + t]; v1 = v1 > 0.f ? v1 : NEG_SLOPE * v1;
      float v2 = as2 + a_l[6 * 1280 + d * 20 + t]; v2 = v2 > 0.f ? v2 : NEG_SLOPE * v2;
      float v3 = as3 + a_l[7 * 1280 + d * 20 + t]; v3 = v3 > 0.f ? v3 : NEG_SLOPE * v3;
      w0 += __expf(v0) * zv.x;
      w1 += __expf(v1) * zv.y;
      w2 += __expf(v2) * zv.z;
      w3 += __expf(v3) * zv.w;
    }
    w_l[src * 64 +  0 + t] = w0;
    w_l[src * 64 + 16 + t] = w1;
    w_l[src * 64 + 32 + t] = w2;
    w_l[src * 64 + 48 + t] = w3;
  }
  __syncthreads();

  // ---------------- pass 2: y[h][c][t] = sum_n w[n][h][t] * x[b][c][n][t] ------
  {
    const int t2 = tid & 15, cl = tid >> 4;  // cl 0..63; c = cl, cl+64
    const float* xA = x + ((size_t)(b * C_ + cl) * N_) * T_ + t0 + t2;
    const float* xB = xA + (size_t)64 * NT_;
    float yrA[4] = {0.f, 0.f, 0.f, 0.f};
    float yrB[4] = {0.f, 0.f, 0.f, 0.f};
    for (int nb = 0; nb < 8; ++nb) {
      float xa[8], xb_[8];
#pragma unroll
      for (int u = 0; u < 8; ++u) {
        xa[u]  = xA[(size_t)(nb * 8 + u) * T_];
        xb_[u] = xB[(size_t)(nb * 8 + u) * T_];
      }
#pragma unroll
      for (int u = 0; u < 8; ++u) {
        const int n = nb * 8 + u;
        float w0 = w_l[n * 64 +  0 + t2];
        float w1 = w_l[n * 64 + 16 + t2];
        float w2 = w_l[n * 64 + 32 + t2];
        float w3 = w_l[n * 64 + 48 + t2];
        yrA[0] = fmaf(xa[u], w0, yrA[0]); yrA[1] = fmaf(xa[u], w1, yrA[1]);
        yrA[2] = fmaf(xa[u], w2, yrA[2]); yrA[3] = fmaf(xa[u], w3, yrA[3]);
        yrB[0] = fmaf(xb_[u], w0, yrB[0]); yrB[1] = fmaf(xb_[u], w1, yrB[1]);
        yrB[2] = fmaf(xb_[u], w2, yrB[2]); yrB[3] = fmaf(xb_[u], w3, yrB[3]);
      }
    }
    float* y_l = a_l;                       // overlay (a dead after C)
#pragma unroll
    for (int h = 0; h < 4; ++h) {
      y_l[h * 2176 + cl * 17 + t2]        = yrA[h];
      y_l[h * 2176 + (cl + 64) * 17 + t2] = yrB[h];
    }
  }
  __syncthreads();

  // ---------------- pass 3: stage W; out = BN(y·W + bias) ----------------------
  {
    const float4* Wm4 = reinterpret_cast<const float4*>(Wm);
    float4* ws4 = reinterpret_cast<float4*>(wstage);
#pragma unroll
    for (int r = 0; r < 4; ++r) ws4[r * 1024 + tid] = Wm4[r * 1024 + tid];
  }
  __syncthreads();
  {
    const int t3 = tid & 15;
    const int g = tid >> 4;        // 0..63
    const int h = g >> 4;          // 0..3
    const int dp = g & 15;         // d = dp*2, dp*2+1
    const float* y_l = a_l;
    float acc0 = 0.f, acc1 = 0.f;
#pragma unroll 8
    for (int c = 0; c < C_; ++c) {
      float yv = y_l[h * 2176 + c * 17 + t3];
      const float2 wv = *reinterpret_cast<const float2*>(
          &wstage[(c * H_ + h) * D_ + dp * 2]);
      acc0 = fmaf(yv, wv.x, acc0);
      acc1 = fmaf(yv, wv.y, acc1);
    }
    int oc = h * D_ + dp * 2;
    float s0 = bn_gamma[oc] * rsqrtf(bn_var[oc] + BN_EPS);
    float s1 = bn_gamma[oc + 1] * rsqrtf(bn_var[oc + 1] + BN_EPS);
    out[((size_t)b * OUT_ + oc) * T_ + t0 + t3] =
        (acc0 + bias[oc]) * s0 + bn_beta[oc] - bn_mean[oc] * s0;
    out[((size_t)b * OUT_ + oc + 1) * T_ + t0 + t3] =
        (acc1 + bias[oc + 1]) * s1 + bn_beta[oc + 1] - bn_mean[oc + 1] * s1;
  }
}

extern "C" void kernel_launch(void* const* d_in, const int* in_sizes, int n_in,
                              void* d_out, int out_size, void* d_ws, size_t ws_size,
                              hipStream_t stream) {
  const float* x        = (const float*)d_in[0];
  const float* W        = (const float*)d_in[1];
  const float* att_src  = (const float*)d_in[2];
  const float* att_dst  = (const float*)d_in[3];
  const float* bias     = (const float*)d_in[4];
  const float* bn_gamma = (const float*)d_in[5];
  const float* bn_beta  = (const float*)d_in[6];
  const float* bn_mean  = (const float*)d_in[7];
  const float* bn_var   = (const float*)d_in[8];
  const int* edge_index = (const int*)d_in[9];
  float* out = (float*)d_out;

  char* ws = (char*)d_ws;
  float* wa   = (float*)ws;            // 4 KB
  int* iOff_g = (int*)(ws + 4096);     // 65 ints
  int* iSrc_g = (int*)(ws + 4608);     // 320 ints
  int* oOff_g = (int*)(ws + 6144);     // 65 ints
  int* oDst_g = (int*)(ws + 6656);     // 320 ints

  setup_kernel<<<1, 256, 0, stream>>>(W, att_src, att_dst, edge_index, wa,
                                      iOff_g, iSrc_g, oOff_g, oDst_g);
  mega_kernel<<<256, 1024, 0, stream>>>(x, wa, W, iOff_g, iSrc_g, oOff_g, oDst_g,
                                        bias, bn_gamma, bn_beta, bn_mean, bn_var,
                                        out);
}